// Round 10
// baseline (5583.273 us; speedup 1.0000x reference)
//
#include <hip/hip_runtime.h>

#define B_SZ 4096
#define D_SZ 1024
#define K_SZ 32
#define NT   32          // K-depth steps of 32

typedef _Float16 h16x8 __attribute__((ext_vector_type(8)));
typedef float f32x4 __attribute__((ext_vector_type(4)));
typedef float f32x2 __attribute__((ext_vector_type(2)));
typedef unsigned int u32x2 __attribute__((ext_vector_type(2)));
typedef unsigned int u32x4 __attribute__((ext_vector_type(4)));
typedef unsigned short u16x4 __attribute__((ext_vector_type(4)));

// async global->LDS, 16B per lane (wave-uniform LDS base + lane*16)
#define GLOAD16(gp, sp) __builtin_amdgcn_global_load_lds( \
    (const __attribute__((address_space(1))) void*)(gp),  \
    (__attribute__((address_space(3))) void*)(sp), 16, 0, 0)

// fp32 -> fp16 hi + fp16 lo*2^11 (lo scaled to stay normal)
__device__ __forceinline__ void split1(float x, _Float16& h, _Float16& l) {
    h = (_Float16)x;
    l = (_Float16)((x - (float)h) * 2048.0f);
}

// ---------------- prepass: W[k][d][e] f32 -> Wt_h/Wt_l[k][e][d] fp16 ----------------
__global__ __launch_bounds__(256)
void ntl_prep_w(const float* __restrict__ W,
                _Float16* __restrict__ Wh, _Float16* __restrict__ Wl) {
    __shared__ float tile[64 * 69];
    const int bid = blockIdx.x;
    const int k  = bid >> 8;
    const int d0 = ((bid >> 4) & 15) << 6;
    const int e0 = (bid & 15) << 6;
    const int t  = threadIdx.x;
    const int r  = t >> 4;
    const int c4 = (t & 15) << 2;

    const float* src = W + ((size_t)k * D_SZ + d0) * D_SZ + e0;
    #pragma unroll
    for (int p = 0; p < 4; ++p) {
        f32x4 v = *(const f32x4*)(src + (size_t)(p * 16 + r) * D_SZ + c4);
        float* dst = &tile[(p * 16 + r) * 69 + c4];
        dst[0] = v[0]; dst[1] = v[1]; dst[2] = v[2]; dst[3] = v[3];
    }
    __syncthreads();
    #pragma unroll
    for (int p = 0; p < 4; ++p) {
        const int e = p * 16 + r;
        u16x4 hh, ll;
        #pragma unroll
        for (int q = 0; q < 4; ++q) {
            float v = tile[(c4 + q) * 69 + e];
            _Float16 h, l;
            split1(v, h, l);
            hh[q] = __builtin_bit_cast(unsigned short, h);
            ll[q] = __builtin_bit_cast(unsigned short, l);
        }
        const size_t o = ((size_t)k * D_SZ + e0 + e) * D_SZ + d0 + c4;
        *(u16x4*)(Wh + o) = hh;
        *(u16x4*)(Wl + o) = ll;
    }
}

// ---------------- prepass: e1 f32 -> e1_h/e1_l fp16 ----------------
__global__ __launch_bounds__(256)
void ntl_prep_e(const float* __restrict__ e1,
                _Float16* __restrict__ eh, _Float16* __restrict__ el) {
    const size_t i = ((size_t)blockIdx.x * 256 + threadIdx.x) * 4;
    f32x4 v = *(const f32x4*)(e1 + i);
    u16x4 hh, ll;
    #pragma unroll
    for (int q = 0; q < 4; ++q) {
        _Float16 h, l;
        split1(v[q], h, l);
        hh[q] = __builtin_bit_cast(unsigned short, h);
        ll[q] = __builtin_bit_cast(unsigned short, l);
    }
    *(u16x4*)(eh + i) = hh;
    *(u16x4*)(el + i) = ll;
}

// ---------------- main bilinear: 128x128, BK=32, 4 waves, SINGLE-buffer, 4 blocks/CU ----
// R8 read/write patterns + XCD placement, unchanged. ONE change: occupancy.
// Single 32KB buffer (A 16K | B 16K), plain STAGE -> sync -> compute -> sync loop,
// __launch_bounds__(256,4): LDS 4x32=128KB, VGPR<=128 -> 16 waves/CU (4/SIMD).
// Cross-block TLP hides each block's exposed staging drain (R5->R2 scaling evidence:
// 1 blk 34% MfmaUtil, 2 blk 53-57%; predict 4 blk ~70%+).
__global__ __launch_bounds__(256, 4)
void ntl_bilinear9(const _Float16* __restrict__ eh, const _Float16* __restrict__ el,
                   const _Float16* __restrict__ Wh, const _Float16* __restrict__ Wl,
                   const float* __restrict__ e2, float* __restrict__ out) {
    __shared__ __align__(16) char lds[32768];

    const int bid = blockIdx.x;
    const int xcd = bid & 7;           // HW round-robin: bid%8 -> XCD
    const int seq = bid >> 3;          // 0..1023, in-order within an XCD
    const int k   = seq >> 5;          // 32 (slowest: W[k] streams once)
    const int e_t = (seq >> 2) & 7;    // 8 e-tiles
    const int bl  = seq & 3;           // 4 b-tiles per XCD (innermost)
    const int b0  = (xcd * 4 + bl) * 128;
    const int e0  = e_t * 128;

    const int t  = threadIdx.x;
    const int l  = t & 63;
    const int w  = t >> 6;             // 0..3
    const int wr = (w >> 1) * 64;
    const int wc = (w & 1) * 64;
    const int lrow = l & 15;
    const int lq   = l >> 4;           // 0..3

    f32x4 acc1[4][4];   // hi*hi
    f32x4 acc2[4][4];   // hi*lo' + lo'*hi  (scale 2^11)
    #pragma unroll
    for (int m = 0; m < 4; ++m)
        #pragma unroll
        for (int n = 0; n < 4; ++n) {
            acc1[m][n] = f32x4{0.f, 0.f, 0.f, 0.f};
            acc2[m][n] = f32x4{0.f, 0.f, 0.f, 0.f};
        }

    // ---- staging source addressing ----
    // instr i of wave w covers lines w*32 + i*8 + (l>>3); lane slot = l&7;
    // content sx = (l&7) ^ (l>>3):  hl = sx>>2 (base select), lq_s = sx&3 (k-granule)
    const int sline = l >> 3;
    const int sx    = (l & 7) ^ sline;
    const int hl    = sx >> 2;
    const int lqs   = sx & 3;

    const _Float16* aBase = hl ? el : eh;
    const _Float16* bBase = hl ? Wl : Wh;
    const _Float16* gA[4];
    const _Float16* gB[4];
    #pragma unroll
    for (int i = 0; i < 4; ++i) {
        const int row = w * 32 + i * 8 + sline;
        gA[i] = aBase + (size_t)(b0 + row) * D_SZ + lqs * 8;
        gB[i] = bBase + ((size_t)k * D_SZ + e0 + row) * D_SZ + lqs * 8;
    }
    const int sOff = w * 32 * 128;     // byte offset of wave's first line

#define STAGE(ktv) do {                                                  \
        const size_t kb = (size_t)(ktv) * 32;                            \
        GLOAD16(gA[0] + kb, lds + sOff);                                 \
        GLOAD16(gA[1] + kb, lds + sOff + 1024);                          \
        GLOAD16(gA[2] + kb, lds + sOff + 2048);                         \
        GLOAD16(gA[3] + kb, lds + sOff + 3072);                          \
        GLOAD16(gB[0] + kb, lds + 16384 + sOff);                         \
        GLOAD16(gB[1] + kb, lds + 16384 + sOff + 1024);                  \
        GLOAD16(gB[2] + kb, lds + 16384 + sOff + 2048);                  \
        GLOAD16(gB[3] + kb, lds + 16384 + sOff + 3072);                  \
    } while (0)

    // ---- ds_read offsets (R2-verified conflict-free family) ----
    // content c read at slot (c ^ (r&7)); a_h: c=lq, a_l: c=4|lq (within line)
    int aoffH[4], aoffL[4], boffH[4], boffL[4];
    #pragma unroll
    for (int m = 0; m < 4; ++m) {
        const int r = wr + m * 16 + lrow;
        aoffH[m] = r * 128 + ((lq       ^ (r & 7)) << 4);
        aoffL[m] = r * 128 + (((4 | lq) ^ (r & 7)) << 4);
    }
    #pragma unroll
    for (int n = 0; n < 4; ++n) {
        const int r = wc + n * 16 + lrow;
        boffH[n] = 16384 + r * 128 + ((lq       ^ (r & 7)) << 4);
        boffL[n] = 16384 + r * 128 + (((4 | lq) ^ (r & 7)) << 4);
    }

    for (int kt = 0; kt < NT; ++kt) {
        STAGE(kt);
        __syncthreads();               // vmcnt(0)+lgkm(0) drain: buffer ready

        h16x8 a_h[4], a_l[4];
        #pragma unroll
        for (int m = 0; m < 4; ++m) {
            a_h[m] = *(const h16x8*)(lds + aoffH[m]);
            a_l[m] = *(const h16x8*)(lds + aoffL[m]);
        }
        #pragma unroll
        for (int n = 0; n < 4; ++n) {
            h16x8 b_h = *(const h16x8*)(lds + boffH[n]);
            h16x8 b_l = *(const h16x8*)(lds + boffL[n]);
            #pragma unroll
            for (int m = 0; m < 4; ++m) {
                acc1[m][n] = __builtin_amdgcn_mfma_f32_16x16x32_f16(a_h[m], b_h, acc1[m][n], 0, 0, 0);
                acc2[m][n] = __builtin_amdgcn_mfma_f32_16x16x32_f16(a_h[m], b_l, acc2[m][n], 0, 0, 0);
                acc2[m][n] = __builtin_amdgcn_mfma_f32_16x16x32_f16(a_l[m], b_h, acc2[m][n], 0, 0, 0);
            }
        }

        __syncthreads();               // all waves done reading before next STAGE overwrites
    }
#undef STAGE

    // ---- epilogue: T .* e2, reduce over this block's 128 e-columns ----
    // C/D layout (m89): col = lane&15, row = (lane>>4)*4 + j
    float rsum[16];
    #pragma unroll
    for (int i = 0; i < 16; ++i) rsum[i] = 0.f;

    #pragma unroll
    for (int m = 0; m < 4; ++m) {
        #pragma unroll
        for (int n = 0; n < 4; ++n) {
            const int col = e0 + wc + n * 16 + lrow;
            #pragma unroll
            for (int j = 0; j < 4; ++j) {
                const int row = b0 + wr + m * 16 + lq * 4 + j;
                float tv = acc1[m][n][j] + acc2[m][n][j] * (1.0f / 2048.0f);
                rsum[m * 4 + j] += tv * e2[(size_t)row * D_SZ + col];
            }
        }
    }

    #pragma unroll
    for (int i = 0; i < 16; ++i) {
        float v = rsum[i];
        v += __shfl_xor(v, 1, 16);
        v += __shfl_xor(v, 2, 16);
        v += __shfl_xor(v, 4, 16);
        v += __shfl_xor(v, 8, 16);
        if (lrow == 0) {
            const int row = b0 + wr + (i >> 2) * 16 + lq * 4 + (i & 3);
            atomicAdd(out + (size_t)k * B_SZ + row, v);
        }
    }
}

// ================= fallback path (round-1 bilinear, used if ws too small) =================
__device__ __forceinline__ int swz_fb(int row, int byte_in_row) {
    int slot = byte_in_row >> 4;
    int in   = byte_in_row & 15;
    return row * 128 + (((slot ^ (row & 7)) << 4) | in);
}
__device__ __forceinline__ void split_fb(float x, unsigned short& h, unsigned short& l) {
    _Float16 hf = (_Float16)x;
    float hff = (float)hf;
    _Float16 lf = (_Float16)((x - hff) * 2048.0f);
    h = __builtin_bit_cast(unsigned short, hf);
    l = __builtin_bit_cast(unsigned short, lf);
}
__global__ __launch_bounds__(256, 2)
void ntl_bilinear_fb(const float* __restrict__ e1, const float* __restrict__ e2,
                     const float* __restrict__ W, float* __restrict__ out) {
    __shared__ __align__(16) char smem[65536];
    char* const Ah = smem;
    char* const Al = smem + 16384;
    char* const Bh = smem + 32768;
    char* const Bl = smem + 49152;
    const int bid = blockIdx.x;
    const int k   = bid >> 8;
    const int rem = bid & 255;
    const int b0  = (rem >> 3) * 128;
    const int e0  = (rem & 7) * 128;
    const int t  = threadIdx.x;
    const int l  = t & 63;
    const int w  = t >> 6;
    const int wr = (w >> 1) * 64;
    const int wc = (w & 1) * 64;
    const int lrow = l & 15;
    const int lq   = l >> 4;
    f32x4 acc1[4][4], acc2[4][4];
    #pragma unroll
    for (int m = 0; m < 4; ++m)
        #pragma unroll
        for (int n = 0; n < 4; ++n) {
            acc1[m][n] = f32x4{0.f, 0.f, 0.f, 0.f};
            acc2[m][n] = f32x4{0.f, 0.f, 0.f, 0.f};
        }
    const int sa_row = t >> 4;
    const int sa_cg  = (t & 15) * 4;
    const int sb_e   = t & 127;
    const int sb_dg  = t >> 7;
    const float* const e1b = e1 + (size_t)b0 * D_SZ;
    const float* const wb  = W + ((size_t)k * D_SZ) * D_SZ + e0 + sb_e;
    for (int kt = 0; kt < 16; ++kt) {
        const int d0 = kt * 64;
        #pragma unroll
        for (int p = 0; p < 8; ++p) {
            const int r = sa_row + p * 16;
            f32x4 vv4 = *(const f32x4*)(e1b + (size_t)r * D_SZ + d0 + sa_cg);
            unsigned short hh[4], ll[4];
            #pragma unroll
            for (int qq = 0; qq < 4; ++qq) split_fb(vv4[qq], hh[qq], ll[qq]);
            u32x2 hv = { (unsigned)hh[0] | ((unsigned)hh[1] << 16),
                         (unsigned)hh[2] | ((unsigned)hh[3] << 16) };
            u32x2 lv = { (unsigned)ll[0] | ((unsigned)ll[1] << 16),
                         (unsigned)ll[2] | ((unsigned)ll[3] << 16) };
            const int ad = swz_fb(r, sa_cg * 2);
            *(u32x2*)(Ah + ad) = hv;
            *(u32x2*)(Al + ad) = lv;
        }
        {
            const float* ws2 = wb + (size_t)(d0 + sb_dg * 32) * D_SZ;
            #pragma unroll
            for (int gg = 0; gg < 4; ++gg) {
                unsigned short hh[8], ll[8];
                #pragma unroll
                for (int i = 0; i < 8; ++i)
                    split_fb(ws2[(size_t)(gg * 8 + i) * D_SZ], hh[i], ll[i]);
                u32x4 hv = { (unsigned)hh[0] | ((unsigned)hh[1] << 16),
                             (unsigned)hh[2] | ((unsigned)hh[3] << 16),
                             (unsigned)hh[4] | ((unsigned)hh[5] << 16),
                             (unsigned)hh[6] | ((unsigned)hh[7] << 16) };
                u32x4 lv = { (unsigned)ll[0] | ((unsigned)ll[1] << 16),
                             (unsigned)ll[2] | ((unsigned)ll[3] << 16),
                             (unsigned)ll[4] | ((unsigned)ll[5] << 16),
                             (unsigned)ll[6] | ((unsigned)ll[7] << 16) };
                const int ad = swz_fb(sb_e, (sb_dg * 32 + gg * 8) * 2);
                *(u32x4*)(Bh + ad) = hv;
                *(u32x4*)(Bl + ad) = lv;
            }
        }
        __syncthreads();
        #pragma unroll
        for (int kk = 0; kk < 2; ++kk) {
            const int kb = kk * 64 + lq * 16;
            h16x8 a_h[4], a_l[4];
            #pragma unroll
            for (int m = 0; m < 4; ++m) {
                const int ad = swz_fb(wr + m * 16 + lrow, kb);
                a_h[m] = *(const h16x8*)(Ah + ad);
                a_l[m] = *(const h16x8*)(Al + ad);
            }
            #pragma unroll
            for (int n = 0; n < 4; ++n) {
                const int bd = swz_fb(wc + n * 16 + lrow, kb);
                h16x8 b_h = *(const h16x8*)(Bh + bd);
                h16x8 b_l = *(const h16x8*)(Bl + bd);
                #pragma unroll
                for (int m = 0; m < 4; ++m) {
                    acc1[m][n] = __builtin_amdgcn_mfma_f32_16x16x32_f16(a_h[m], b_h, acc1[m][n], 0, 0, 0);
                    acc2[m][n] = __builtin_amdgcn_mfma_f32_16x16x32_f16(a_h[m], b_l, acc2[m][n], 0, 0, 0);
                    acc2[m][n] = __builtin_amdgcn_mfma_f32_16x16x32_f16(a_l[m], b_h, acc2[m][n], 0, 0, 0);
                }
            }
        }
        __syncthreads();
    }
    float rsum[16];
    #pragma unroll
    for (int i = 0; i < 16; ++i) rsum[i] = 0.f;
    #pragma unroll
    for (int m = 0; m < 4; ++m) {
        #pragma unroll
        for (int n = 0; n < 4; ++n) {
            const int col = e0 + wc + n * 16 + lrow;
            #pragma unroll
            for (int jq = 0; jq < 4; ++jq) {
                const int row = b0 + wr + m * 16 + lq * 4 + jq;
                float tv = acc1[m][n][jq] + acc2[m][n][jq] * (1.0f / 2048.0f);
                rsum[m * 4 + jq] += tv * e2[(size_t)row * D_SZ + col];
            }
        }
    }
    #pragma unroll
    for (int i = 0; i < 16; ++i) {
        float vv = rsum[i];
        vv += __shfl_xor(vv, 1, 16);
        vv += __shfl_xor(vv, 2, 16);
        vv += __shfl_xor(vv, 4, 16);
        vv += __shfl_xor(vv, 8, 16);
        if (lrow == 0) {
            const int row = b0 + wr + (i >> 2) * 16 + lq * 4 + (i & 3);
            atomicAdd(out + (size_t)k * B_SZ + row, vv);
        }
    }
}

// ---------------- ff / sumb / tanh ----------------
__global__ __launch_bounds__(256)
void ntl_ff(const float* __restrict__ e1, const float* __restrict__ e2,
            const float* __restrict__ V, float* __restrict__ out) {
    __shared__ float vt[32 * 258];
    const int t  = threadIdx.x;
    const int c  = t & 31;
    const int rl = t >> 5;
    const int r  = blockIdx.x * 8 + rl;
    float acc = 0.f;
    for (int j0 = 0; j0 < 2 * D_SZ; j0 += 256) {
        __syncthreads();
        #pragma unroll
        for (int i = 0; i < 32; ++i) {
            const int f = i * 256 + t;
            vt[(f & 31) * 258 + (f >> 5)] = V[(size_t)j0 * K_SZ + f];
        }
        __syncthreads();
        const float* src = (j0 < D_SZ) ? (e1 + (size_t)r * D_SZ + j0)
                                       : (e2 + (size_t)r * D_SZ + (j0 - D_SZ));
        #pragma unroll 8
        for (int jj = 0; jj < 256; jj += 2) {
            f32x2 a  = *(const f32x2*)(src + jj);
            f32x2 vv = *(const f32x2*)(&vt[c * 258 + jj]);
            acc += a[0] * vv[0] + a[1] * vv[1];
        }
    }
    out[(size_t)r * K_SZ + c] += acc;
}

__global__ void ntl_sumb(const float* __restrict__ b, float* __restrict__ ws) {
    __shared__ float red[256];
    const int t = threadIdx.x;
    red[t] = b[t] + b[t + 256] + b[t + 512] + b[t + 768];
    __syncthreads();
    for (int s = 128; s > 0; s >>= 1) {
        if (t < s) red[t] += red[t + s];
        __syncthreads();
    }
    if (t == 0) ws[0] = red[0];
}

__global__ void ntl_tanh(float* __restrict__ out, const float* __restrict__ ws) {
    const int p = blockIdx.x * 256 + threadIdx.x;
    out[p] = tanhf(out[p] + ws[0]);
}

extern "C" void kernel_launch(void* const* d_in, const int* in_sizes, int n_in,
                              void* d_out, int out_size, void* d_ws, size_t ws_size,
                              hipStream_t stream) {
    const float* e1 = (const float*)d_in[0];
    const float* e2 = (const float*)d_in[1];
    const float* W  = (const float*)d_in[2];
    const float* V  = (const float*)d_in[3];
    const float* b  = (const float*)d_in[4];
    float* out = (float*)d_out;

    const size_t WT = (size_t)K_SZ * D_SZ * D_SZ;
    const size_t ET = (size_t)B_SZ * D_SZ;
    const size_t need = (2 * WT + 2 * ET) * sizeof(_Float16) + 16;

    hipMemsetAsync(d_out, 0, (size_t)B_SZ * K_SZ * sizeof(float), stream);

    if (ws_size >= need) {
        _Float16* Wh = (_Float16*)d_ws;
        _Float16* Wl = Wh + WT;
        _Float16* ehp = Wl + WT;
        _Float16* elp = ehp + ET;
        float* sb = (float*)(elp + ET);
        ntl_sumb<<<1, 256, 0, stream>>>(b, sb);
        ntl_prep_w<<<dim3(K_SZ * 256), dim3(256), 0, stream>>>(W, Wh, Wl);
        ntl_prep_e<<<dim3((int)(ET / 1024)), dim3(256), 0, stream>>>(e1, ehp, elp);
        ntl_bilinear9<<<dim3(K_SZ * 256), dim3(256), 0, stream>>>(ehp, elp, Wh, Wl, e2, out);
        ntl_ff<<<dim3(B_SZ / 8), dim3(256), 0, stream>>>(e1, e2, V, out);
        ntl_tanh<<<dim3((B_SZ * K_SZ) / 256), dim3(256), 0, stream>>>(out, sb);
    } else {
        float* sb = (float*)d_ws;
        ntl_sumb<<<1, 256, 0, stream>>>(b, sb);
        ntl_bilinear_fb<<<dim3(K_SZ * 256), dim3(256), 0, stream>>>(e1, e2, W, out);
        ntl_ff<<<dim3(B_SZ / 8), dim3(256), 0, stream>>>(e1, e2, V, out);
        ntl_tanh<<<dim3((B_SZ * K_SZ) / 256), dim3(256), 0, stream>>>(out, sb);
    }
}